// Round 1
// baseline (667.379 us; speedup 1.0000x reference)
//
#include <hip/hip_runtime.h>
#include <math.h>

// Problem constants (B=64, C=128, H=W=56)
#define HW 3136
#define NCHUNK 3136          // 64 batches * 49 chunks of 64 samples
#define M_TOT 200704.0f
#define EPSV 1e-5f

// ---------------------------------------------------------------------------
// Kernel 1: partial Gram (X @ X^T) + per-channel sums over sample chunks.
// grid = slots (<=512), block = 256. Each block owns one partial slot.
// LDS tile xs[128][65]: pad 65 + per-thread sample rotation sp=(s+tj)&63
// makes both av (row i0..i0+7) and bv (row j0..j0+7) reads <=2-way conflicts.
// ---------------------------------------------------------------------------
__global__ __launch_bounds__(256, 2) void gram_k(const float* __restrict__ x,
                                                 float* __restrict__ partG,
                                                 float* __restrict__ partS,
                                                 int nchunkStride) {
  __shared__ float xs[128 * 65];
  const int t = threadIdx.x;
  const int ti = t >> 4, tj = t & 15;
  const int i0 = ti * 8, j0 = tj * 8;

  float acc[8][8];
#pragma unroll
  for (int a = 0; a < 8; ++a)
#pragma unroll
    for (int b = 0; b < 8; ++b) acc[a][b] = 0.f;
  float ssum = 0.f;

  for (int chunk = blockIdx.x; chunk < NCHUNK; chunk += nchunkStride) {
    const int b = chunk / 49;
    const int s0 = (chunk % 49) * 64;
    __syncthreads();  // protect xs from previous iteration's readers
#pragma unroll
    for (int i = 0; i < 8; ++i) {
      const int idx4 = i * 256 + t;
      const int c = idx4 >> 4, q = idx4 & 15;
      const float4 v =
          *(const float4*)(x + (size_t)(b * 128 + c) * HW + s0 + q * 4);
      float* d = &xs[c * 65 + q * 4];
      d[0] = v.x; d[1] = v.y; d[2] = v.z; d[3] = v.w;
    }
    __syncthreads();
#pragma unroll 4
    for (int s = 0; s < 64; ++s) {
      const int sp = (s + tj) & 63;  // bank-conflict-avoiding rotation
      float av[8], bv[8];
#pragma unroll
      for (int k = 0; k < 8; ++k) av[k] = xs[(i0 + k) * 65 + sp];
#pragma unroll
      for (int l = 0; l < 8; ++l) bv[l] = xs[(j0 + l) * 65 + sp];
#pragma unroll
      for (int k = 0; k < 8; ++k)
#pragma unroll
        for (int l = 0; l < 8; ++l) acc[k][l] += av[k] * bv[l];
    }
    if (t < 128) {  // channel sums (waves 0,1 only; uniform branch)
      float sloc = 0.f;
      for (int s = 0; s < 64; ++s) sloc += xs[t * 65 + s];
      ssum += sloc;
    }
  }

  float* pg = partG + (size_t)blockIdx.x * 16384;
#pragma unroll
  for (int k = 0; k < 8; ++k)
#pragma unroll
    for (int l = 0; l < 8; l += 4) {
      *(float4*)(pg + (i0 + k) * 128 + j0 + l) = make_float4(
          acc[k][l], acc[k][l + 1], acc[k][l + 2], acc[k][l + 3]);
    }
  if (t < 128) partS[blockIdx.x * 128 + t] = ssum;
}

// ---------------------------------------------------------------------------
// Kernel 2: reduce partial Grams -> G (16384), partial sums -> Sb (128).
// grid = 128, block = 256 (two slot-groups per entry).
// ---------------------------------------------------------------------------
__global__ __launch_bounds__(256) void reduce_k(const float* __restrict__ partG,
                                                const float* __restrict__ partS,
                                                float* __restrict__ G,
                                                float* __restrict__ Sb,
                                                int slots) {
  const int t = threadIdx.x;
  const int e = blockIdx.x * 128 + (t & 127);
  const int g = t >> 7;
  float a = 0.f;
  for (int s = g; s < slots; s += 2) a += partG[(size_t)s * 16384 + e];
  __shared__ float red[256];
  red[t] = a;
  __syncthreads();
  if (g == 0) G[e] = red[t] + red[t + 128];
  if (blockIdx.x == 0 && t < 128) {
    float sa = 0.f;
    for (int s = 0; s < slots; ++s) sa += partS[s * 128 + t];
    Sb[t] = sa;
  }
}

// ---------------------------------------------------------------------------
// Kernel 3: Sigma = (G - S S^T/m)/m + eps I; trace-normalize -> SigmaN;
// P0 = I; Sb -> mean (in place); scal[0] = sqrt(1/trace). 1 block x 256.
// ---------------------------------------------------------------------------
__global__ __launch_bounds__(256) void sigma_k(const float* __restrict__ G,
                                               float* __restrict__ Sb,
                                               float* __restrict__ SigmaN,
                                               float* __restrict__ Pa,
                                               float* __restrict__ scal) {
  const int t = threadIdx.x;
  const float rm = 1.0f / M_TOT;
  float trl = 0.f;
#pragma unroll 4
  for (int i = 0; i < 64; ++i) {
    const int e = i * 256 + t;
    const int r = e >> 7, c = e & 127;
    float v = (G[e] - Sb[r] * Sb[c] * rm) * rm + ((r == c) ? EPSV : 0.f);
    SigmaN[e] = v;
    Pa[e] = (r == c) ? 1.f : 0.f;
    if (r == c) trl += v;
  }
  __shared__ float red[256];
  red[t] = trl;
  __syncthreads();
  for (int off = 128; off > 0; off >>= 1) {
    if (t < off) red[t] += red[t + off];
    __syncthreads();
  }
  const float rTr = 1.0f / red[0];
#pragma unroll 4
  for (int i = 0; i < 64; ++i) {
    const int e = i * 256 + t;
    SigmaN[e] *= rTr;
  }
  if (t < 128) Sb[t] *= rm;  // mean
  if (t == 0) scal[0] = sqrtf(rTr);
}

// ---------------------------------------------------------------------------
// Kernel 4: one fused Newton iteration: Pout = 0.5*(3P - ((P@P)@P)@SigmaN).
// grid = 16 (8-row strips), block = 256, 16KB LDS, matrices read via L1/L2.
// Reads P (full), writes disjoint strip of Pout (ping-pong buffers).
// ---------------------------------------------------------------------------
__global__ __launch_bounds__(256) void newton_k(const float* __restrict__ P,
                                                const float* __restrict__ SigmaN,
                                                float* __restrict__ Pout) {
  __shared__ float s1[8 * 128];
  __shared__ float s2[8 * 128];
  const int t = threadIdx.x;
  const int r = t >> 5;                 // 0..7 strip-local row
  const int rg = blockIdx.x * 8 + r;    // global row
  const int c0 = (t & 31) * 4;
  const float* prow = P + rg * 128;

  float ax = 0, ay = 0, az = 0, aw = 0;
#pragma unroll 4
  for (int k = 0; k < 128; ++k) {       // P2 = P @ P (strip)
    const float a = prow[k];
    const float4 bv = *(const float4*)(P + k * 128 + c0);
    ax += a * bv.x; ay += a * bv.y; az += a * bv.z; aw += a * bv.w;
  }
  *(float4*)(s1 + r * 128 + c0) = make_float4(ax, ay, az, aw);
  __syncthreads();

  ax = ay = az = aw = 0;
#pragma unroll 4
  for (int k = 0; k < 128; ++k) {       // T = P2 @ P (strip)
    const float a = s1[r * 128 + k];
    const float4 bv = *(const float4*)(P + k * 128 + c0);
    ax += a * bv.x; ay += a * bv.y; az += a * bv.z; aw += a * bv.w;
  }
  *(float4*)(s2 + r * 128 + c0) = make_float4(ax, ay, az, aw);
  __syncthreads();

  ax = ay = az = aw = 0;
#pragma unroll 4
  for (int k = 0; k < 128; ++k) {       // U = T @ SigmaN (strip)
    const float a = s2[r * 128 + k];
    const float4 bv = *(const float4*)(SigmaN + k * 128 + c0);
    ax += a * bv.x; ay += a * bv.y; az += a * bv.z; aw += a * bv.w;
  }
  const float4 pv = *(const float4*)(prow + c0);
  *(float4*)(Pout + rg * 128 + c0) =
      make_float4(0.5f * (3.f * pv.x - ax), 0.5f * (3.f * pv.y - ay),
                  0.5f * (3.f * pv.z - az), 0.5f * (3.f * pv.w - aw));
}

// ---------------------------------------------------------------------------
// Kernel 5: Mt = (sqrt(rTr) * rot @ P)^T  (stored transposed for apply);
// bias[d] = sum_c M[d][c]*mean[c]. grid = 16, block = 256.
// ---------------------------------------------------------------------------
__global__ __launch_bounds__(256) void rotmt_k(const float* __restrict__ rot,
                                               const float* __restrict__ P,
                                               const float* __restrict__ mean,
                                               const float* __restrict__ scal,
                                               float* __restrict__ Mt,
                                               float* __restrict__ bias) {
  const int t = threadIdx.x;
  const int r = t >> 5;
  const int dg = blockIdx.x * 8 + r;
  const int c0 = (t & 31) * 4;
  const float* rrow = rot + dg * 128;

  float ax = 0, ay = 0, az = 0, aw = 0;
#pragma unroll 4
  for (int k = 0; k < 128; ++k) {
    const float a = rrow[k];
    const float4 bv = *(const float4*)(P + k * 128 + c0);
    ax += a * bv.x; ay += a * bv.y; az += a * bv.z; aw += a * bv.w;
  }
  const float sc = scal[0];
  ax *= sc; ay *= sc; az *= sc; aw *= sc;
  Mt[(c0 + 0) * 128 + dg] = ax;
  Mt[(c0 + 1) * 128 + dg] = ay;
  Mt[(c0 + 2) * 128 + dg] = az;
  Mt[(c0 + 3) * 128 + dg] = aw;
  const float4 mv = *(const float4*)(mean + c0);
  float p = ax * mv.x + ay * mv.y + az * mv.z + aw * mv.w;
  for (int off = 16; off > 0; off >>= 1) p += __shfl_down(p, off, 32);
  if ((t & 31) == 0) bias[dg] = p;
}

// ---------------------------------------------------------------------------
// Kernel 6: out[b,d,s] = sum_c M[d][c]*x[b,c,s] - bias[d].
// grid = 784 (strided over 3136 chunks), block = 256, LDS = 32KB x-tile +
// 32KB Mt-half (reloaded from L2 per chunk so x is read from HBM only once).
// ---------------------------------------------------------------------------
__global__ __launch_bounds__(256, 2) void apply_k(const float* __restrict__ x,
                                                  const float* __restrict__ Mt,
                                                  const float* __restrict__ bias,
                                                  float* __restrict__ out) {
  __shared__ float xs[128 * 64];
  __shared__ float ms[128 * 64];
  const int t = threadIdx.x;
  const int sq = t >> 4;          // 0..15 sample quad
  const int dl4 = (t & 15) * 4;   // d-local quad

  for (int chunk = blockIdx.x; chunk < NCHUNK; chunk += gridDim.x) {
    const int b = chunk / 49;
    const int s0 = (chunk % 49) * 64;
    __syncthreads();
#pragma unroll
    for (int i = 0; i < 8; ++i) {
      const int idx4 = i * 256 + t;
      const int c = idx4 >> 4, q = idx4 & 15;
      *(float4*)(xs + c * 64 + q * 4) =
          *(const float4*)(x + (size_t)(b * 128 + c) * HW + s0 + q * 4);
    }
    __syncthreads();
    for (int half = 0; half < 2; ++half) {
#pragma unroll
      for (int i = 0; i < 8; ++i) {
        const int idx4 = i * 256 + t;
        const int c = idx4 >> 4, dq = idx4 & 15;
        *(float4*)(ms + c * 64 + dq * 4) =
            *(const float4*)(Mt + c * 128 + half * 64 + dq * 4);
      }
      __syncthreads();
      float acc[4][4];
#pragma unroll
      for (int i = 0; i < 4; ++i)
#pragma unroll
        for (int j = 0; j < 4; ++j) acc[i][j] = 0.f;
#pragma unroll 8
      for (int c = 0; c < 128; ++c) {
        const float4 mv = *(const float4*)(ms + c * 64 + dl4);
        const float4 xv = *(const float4*)(xs + c * 64 + sq * 4);
        const float mvA[4] = {mv.x, mv.y, mv.z, mv.w};
        const float xvA[4] = {xv.x, xv.y, xv.z, xv.w};
#pragma unroll
        for (int i = 0; i < 4; ++i)
#pragma unroll
          for (int j = 0; j < 4; ++j) acc[i][j] += mvA[i] * xvA[j];
      }
      const int dgl = half * 64 + dl4;
      const float4 bv = *(const float4*)(bias + dgl);
      const float bA[4] = {bv.x, bv.y, bv.z, bv.w};
#pragma unroll
      for (int i = 0; i < 4; ++i) {
        *(float4*)(out + (size_t)(b * 128 + dgl + i) * HW + s0 + sq * 4) =
            make_float4(acc[i][0] - bA[i], acc[i][1] - bA[i],
                        acc[i][2] - bA[i], acc[i][3] - bA[i]);
      }
      __syncthreads();  // before ms (or next chunk's xs) is overwritten
    }
  }
}

// ---------------------------------------------------------------------------
extern "C" void kernel_launch(void* const* d_in, const int* in_sizes, int n_in,
                              void* d_out, int out_size, void* d_ws,
                              size_t ws_size, hipStream_t stream) {
  const float* x = (const float*)d_in[0];        // (64,128,56,56) fp32
  const float* rot = (const float*)d_in[1];      // (128,128) fp32
  float* out = (float*)d_out;                    // (64,128,56,56) fp32
  float* ws = (float*)d_ws;

  // ws layout (floats)
  float* G      = ws;                // 16384
  float* SigmaN = ws + 16384;        // 16384
  float* Pa     = ws + 32768;        // 16384
  float* Pb     = ws + 49152;        // 16384
  float* Mt     = ws + 65536;        // 16384
  float* Sb     = ws + 81920;        // 128   (sums, then mean)
  float* bias   = ws + 82048;        // 128
  float* scal   = ws + 82176;        // 16
  float* partG  = ws + 82192;        // slots * 16384

  const size_t wsf = ws_size / 4;
  long avail = (long)wsf - 82192;
  int slots = (int)(avail / (16384 + 128));
  if (slots > 512) slots = 512;
  if (slots < 1) slots = 1;
  float* partS = partG + (size_t)slots * 16384;

  gram_k<<<slots, 256, 0, stream>>>(x, partG, partS, slots);
  reduce_k<<<128, 256, 0, stream>>>(partG, partS, G, Sb, slots);
  sigma_k<<<1, 256, 0, stream>>>(G, Sb, SigmaN, Pa, scal);
  float* pin = Pa;
  float* pout = Pb;
  for (int i = 0; i < 5; ++i) {
    newton_k<<<16, 256, 0, stream>>>(pin, SigmaN, pout);
    float* tmp = pin; pin = pout; pout = tmp;
  }
  rotmt_k<<<16, 256, 0, stream>>>(rot, pin, Sb, scal, Mt, bias);
  apply_k<<<784, 256, 0, stream>>>(x, Mt, bias, out);
}

// Round 2
// 497.329 us; speedup vs baseline: 1.3419x; 1.3419x over previous
//
#include <hip/hip_runtime.h>
#include <math.h>

// Problem constants (B=64, C=128, H=W=56)
#define HW 3136
#define NCHUNK 3136          // 64 batches * 49 chunks of 64 samples
#define M_TOT 200704.0f
#define EPSV 1e-5f

// ---------------------------------------------------------------------------
// Kernel 1: partial Gram (X @ X^T) + per-channel sums over sample chunks.
// grid = slots (<=512), block = 256. Each block owns one partial slot.
// LDS tile xs[128][65]: pad 65 + per-thread sample rotation sp=(s+tj)&63
// makes both av (row i0..i0+7) and bv (row j0..j0+7) reads <=2-way conflicts.
// ---------------------------------------------------------------------------
__global__ __launch_bounds__(256, 2) void gram_k(const float* __restrict__ x,
                                                 float* __restrict__ partG,
                                                 float* __restrict__ partS,
                                                 int nchunkStride) {
  __shared__ float xs[128 * 65];
  const int t = threadIdx.x;
  const int ti = t >> 4, tj = t & 15;
  const int i0 = ti * 8, j0 = tj * 8;

  float acc[8][8];
#pragma unroll
  for (int a = 0; a < 8; ++a)
#pragma unroll
    for (int b = 0; b < 8; ++b) acc[a][b] = 0.f;
  float ssum = 0.f;

  for (int chunk = blockIdx.x; chunk < NCHUNK; chunk += nchunkStride) {
    const int b = chunk / 49;
    const int s0 = (chunk % 49) * 64;
    __syncthreads();  // protect xs from previous iteration's readers
#pragma unroll
    for (int i = 0; i < 8; ++i) {
      const int idx4 = i * 256 + t;
      const int c = idx4 >> 4, q = idx4 & 15;
      const float4 v =
          *(const float4*)(x + (size_t)(b * 128 + c) * HW + s0 + q * 4);
      float* d = &xs[c * 65 + q * 4];
      d[0] = v.x; d[1] = v.y; d[2] = v.z; d[3] = v.w;
    }
    __syncthreads();
#pragma unroll 4
    for (int s = 0; s < 64; ++s) {
      const int sp = (s + tj) & 63;  // bank-conflict-avoiding rotation
      float av[8], bv[8];
#pragma unroll
      for (int k = 0; k < 8; ++k) av[k] = xs[(i0 + k) * 65 + sp];
#pragma unroll
      for (int l = 0; l < 8; ++l) bv[l] = xs[(j0 + l) * 65 + sp];
#pragma unroll
      for (int k = 0; k < 8; ++k)
#pragma unroll
        for (int l = 0; l < 8; ++l) acc[k][l] += av[k] * bv[l];
    }
    if (t < 128) {  // channel sums (waves 0,1 only; uniform branch)
      float sloc = 0.f;
      for (int s = 0; s < 64; ++s) sloc += xs[t * 65 + s];
      ssum += sloc;
    }
  }

  float* pg = partG + (size_t)blockIdx.x * 16384;
#pragma unroll
  for (int k = 0; k < 8; ++k)
#pragma unroll
    for (int l = 0; l < 8; l += 4) {
      *(float4*)(pg + (i0 + k) * 128 + j0 + l) = make_float4(
          acc[k][l], acc[k][l + 1], acc[k][l + 2], acc[k][l + 3]);
    }
  if (t < 128) partS[blockIdx.x * 128 + t] = ssum;
}

// ---------------------------------------------------------------------------
// Kernel 2a: stage-A reduction. grid = 32 slot-groups x 16 elem-groups = 512.
// Block (sg,eg): thread t sums partG[s][eg*1024 + t*4 ..+3] over s=sg,sg+32,..
// Fully coalesced float4 reads, ~16 independent loads/thread.
// Blocks with eg==0 also fold partS into part2S.
// ---------------------------------------------------------------------------
__global__ __launch_bounds__(256) void reduce1_k(const float* __restrict__ partG,
                                                 const float* __restrict__ partS,
                                                 float* __restrict__ part2,
                                                 float* __restrict__ part2S,
                                                 int slots) {
  const int t = threadIdx.x;
  const int sg = blockIdx.x & 31;
  const int eg = blockIdx.x >> 5;
  const int e4 = eg * 1024 + t * 4;
  float ax = 0.f, ay = 0.f, az = 0.f, aw = 0.f;
#pragma unroll 4
  for (int s = sg; s < slots; s += 32) {
    const float4 v = *(const float4*)(partG + (size_t)s * 16384 + e4);
    ax += v.x; ay += v.y; az += v.z; aw += v.w;
  }
  *(float4*)(part2 + (size_t)sg * 16384 + e4) = make_float4(ax, ay, az, aw);
  if (eg == 0 && t < 128) {
    float sa = 0.f;
    for (int s = sg; s < slots; s += 32) sa += partS[s * 128 + t];
    part2S[sg * 128 + t] = sa;
  }
}

// ---------------------------------------------------------------------------
// Kernel 2b: stage-B reduction. grid = 16, block = 256. Thread owns float4 of
// G, sums 32 partials (independent loads). Block 0 folds part2S -> Sb.
// ---------------------------------------------------------------------------
__global__ __launch_bounds__(256) void reduce2_k(const float* __restrict__ part2,
                                                 const float* __restrict__ part2S,
                                                 float* __restrict__ G,
                                                 float* __restrict__ Sb) {
  const int t = threadIdx.x;
  const int e4 = blockIdx.x * 1024 + t * 4;
  float ax = 0.f, ay = 0.f, az = 0.f, aw = 0.f;
#pragma unroll
  for (int sg = 0; sg < 32; ++sg) {
    const float4 v = *(const float4*)(part2 + (size_t)sg * 16384 + e4);
    ax += v.x; ay += v.y; az += v.z; aw += v.w;
  }
  *(float4*)(G + e4) = make_float4(ax, ay, az, aw);
  if (blockIdx.x == 0 && t < 128) {
    float sa = 0.f;
#pragma unroll
    for (int sg = 0; sg < 32; ++sg) sa += part2S[sg * 128 + t];
    Sb[t] = sa;
  }
}

// ---------------------------------------------------------------------------
// Kernel 3: Sigma = (G - S S^T/m)/m + eps I; trace-normalize -> SigmaN;
// P0 = I; Sb -> mean (in place); scal[0] = sqrt(1/trace). 1 block x 256.
// ---------------------------------------------------------------------------
__global__ __launch_bounds__(256) void sigma_k(const float* __restrict__ G,
                                               float* __restrict__ Sb,
                                               float* __restrict__ SigmaN,
                                               float* __restrict__ Pa,
                                               float* __restrict__ scal) {
  const int t = threadIdx.x;
  const float rm = 1.0f / M_TOT;
  float trl = 0.f;
#pragma unroll 4
  for (int i = 0; i < 64; ++i) {
    const int e = i * 256 + t;
    const int r = e >> 7, c = e & 127;
    float v = (G[e] - Sb[r] * Sb[c] * rm) * rm + ((r == c) ? EPSV : 0.f);
    SigmaN[e] = v;
    Pa[e] = (r == c) ? 1.f : 0.f;
    if (r == c) trl += v;
  }
  __shared__ float red[256];
  red[t] = trl;
  __syncthreads();
  for (int off = 128; off > 0; off >>= 1) {
    if (t < off) red[t] += red[t + off];
    __syncthreads();
  }
  const float rTr = 1.0f / red[0];
#pragma unroll 4
  for (int i = 0; i < 64; ++i) {
    const int e = i * 256 + t;
    SigmaN[e] *= rTr;
  }
  if (t < 128) Sb[t] *= rm;  // mean
  if (t == 0) scal[0] = sqrtf(rTr);
}

// ---------------------------------------------------------------------------
// Kernel 4: one fused Newton iteration: Pout = 0.5*(3P - ((P@P)@P)@SigmaN).
// grid = 16 (8-row strips), block = 256, 16KB LDS, matrices read via L1/L2.
// Reads P (full), writes disjoint strip of Pout (ping-pong buffers).
// ---------------------------------------------------------------------------
__global__ __launch_bounds__(256) void newton_k(const float* __restrict__ P,
                                                const float* __restrict__ SigmaN,
                                                float* __restrict__ Pout) {
  __shared__ float s1[8 * 128];
  __shared__ float s2[8 * 128];
  const int t = threadIdx.x;
  const int r = t >> 5;                 // 0..7 strip-local row
  const int rg = blockIdx.x * 8 + r;    // global row
  const int c0 = (t & 31) * 4;
  const float* prow = P + rg * 128;

  float ax = 0, ay = 0, az = 0, aw = 0;
#pragma unroll 4
  for (int k = 0; k < 128; ++k) {       // P2 = P @ P (strip)
    const float a = prow[k];
    const float4 bv = *(const float4*)(P + k * 128 + c0);
    ax += a * bv.x; ay += a * bv.y; az += a * bv.z; aw += a * bv.w;
  }
  *(float4*)(s1 + r * 128 + c0) = make_float4(ax, ay, az, aw);
  __syncthreads();

  ax = ay = az = aw = 0;
#pragma unroll 4
  for (int k = 0; k < 128; ++k) {       // T = P2 @ P (strip)
    const float a = s1[r * 128 + k];
    const float4 bv = *(const float4*)(P + k * 128 + c0);
    ax += a * bv.x; ay += a * bv.y; az += a * bv.z; aw += a * bv.w;
  }
  *(float4*)(s2 + r * 128 + c0) = make_float4(ax, ay, az, aw);
  __syncthreads();

  ax = ay = az = aw = 0;
#pragma unroll 4
  for (int k = 0; k < 128; ++k) {       // U = T @ SigmaN (strip)
    const float a = s2[r * 128 + k];
    const float4 bv = *(const float4*)(SigmaN + k * 128 + c0);
    ax += a * bv.x; ay += a * bv.y; az += a * bv.z; aw += a * bv.w;
  }
  const float4 pv = *(const float4*)(prow + c0);
  *(float4*)(Pout + rg * 128 + c0) =
      make_float4(0.5f * (3.f * pv.x - ax), 0.5f * (3.f * pv.y - ay),
                  0.5f * (3.f * pv.z - az), 0.5f * (3.f * pv.w - aw));
}

// ---------------------------------------------------------------------------
// Kernel 5: Mt = (sqrt(rTr) * rot @ P)^T  (stored transposed for apply);
// bias[d] = sum_c M[d][c]*mean[c]. grid = 16, block = 256.
// ---------------------------------------------------------------------------
__global__ __launch_bounds__(256) void rotmt_k(const float* __restrict__ rot,
                                               const float* __restrict__ P,
                                               const float* __restrict__ mean,
                                               const float* __restrict__ scal,
                                               float* __restrict__ Mt,
                                               float* __restrict__ bias) {
  const int t = threadIdx.x;
  const int r = t >> 5;
  const int dg = blockIdx.x * 8 + r;
  const int c0 = (t & 31) * 4;
  const float* rrow = rot + dg * 128;

  float ax = 0, ay = 0, az = 0, aw = 0;
#pragma unroll 4
  for (int k = 0; k < 128; ++k) {
    const float a = rrow[k];
    const float4 bv = *(const float4*)(P + k * 128 + c0);
    ax += a * bv.x; ay += a * bv.y; az += a * bv.z; aw += a * bv.w;
  }
  const float sc = scal[0];
  ax *= sc; ay *= sc; az *= sc; aw *= sc;
  Mt[(c0 + 0) * 128 + dg] = ax;
  Mt[(c0 + 1) * 128 + dg] = ay;
  Mt[(c0 + 2) * 128 + dg] = az;
  Mt[(c0 + 3) * 128 + dg] = aw;
  const float4 mv = *(const float4*)(mean + c0);
  float p = ax * mv.x + ay * mv.y + az * mv.z + aw * mv.w;
  for (int off = 16; off > 0; off >>= 1) p += __shfl_down(p, off, 32);
  if ((t & 31) == 0) bias[dg] = p;
}

// ---------------------------------------------------------------------------
// Kernel 6: out[b,d,s] = sum_c M[d][c]*x[b,c,s] - bias[d].
// grid = 784 (strided over 3136 chunks), block = 256, LDS = 32KB x-tile +
// 32KB Mt-half (reloaded from L2 per chunk so x is read from HBM only once).
// ---------------------------------------------------------------------------
__global__ __launch_bounds__(256, 2) void apply_k(const float* __restrict__ x,
                                                  const float* __restrict__ Mt,
                                                  const float* __restrict__ bias,
                                                  float* __restrict__ out) {
  __shared__ float xs[128 * 64];
  __shared__ float ms[128 * 64];
  const int t = threadIdx.x;
  const int sq = t >> 4;          // 0..15 sample quad
  const int dl4 = (t & 15) * 4;   // d-local quad

  for (int chunk = blockIdx.x; chunk < NCHUNK; chunk += gridDim.x) {
    const int b = chunk / 49;
    const int s0 = (chunk % 49) * 64;
    __syncthreads();
#pragma unroll
    for (int i = 0; i < 8; ++i) {
      const int idx4 = i * 256 + t;
      const int c = idx4 >> 4, q = idx4 & 15;
      *(float4*)(xs + c * 64 + q * 4) =
          *(const float4*)(x + (size_t)(b * 128 + c) * HW + s0 + q * 4);
    }
    __syncthreads();
    for (int half = 0; half < 2; ++half) {
#pragma unroll
      for (int i = 0; i < 8; ++i) {
        const int idx4 = i * 256 + t;
        const int c = idx4 >> 4, dq = idx4 & 15;
        *(float4*)(ms + c * 64 + dq * 4) =
            *(const float4*)(Mt + c * 128 + half * 64 + dq * 4);
      }
      __syncthreads();
      float acc[4][4];
#pragma unroll
      for (int i = 0; i < 4; ++i)
#pragma unroll
        for (int j = 0; j < 4; ++j) acc[i][j] = 0.f;
#pragma unroll 8
      for (int c = 0; c < 128; ++c) {
        const float4 mv = *(const float4*)(ms + c * 64 + dl4);
        const float4 xv = *(const float4*)(xs + c * 64 + sq * 4);
        const float mvA[4] = {mv.x, mv.y, mv.z, mv.w};
        const float xvA[4] = {xv.x, xv.y, xv.z, xv.w};
#pragma unroll
        for (int i = 0; i < 4; ++i)
#pragma unroll
          for (int j = 0; j < 4; ++j) acc[i][j] += mvA[i] * xvA[j];
      }
      const int dgl = half * 64 + dl4;
      const float4 bv = *(const float4*)(bias + dgl);
      const float bA[4] = {bv.x, bv.y, bv.z, bv.w};
#pragma unroll
      for (int i = 0; i < 4; ++i) {
        *(float4*)(out + (size_t)(b * 128 + dgl + i) * HW + s0 + sq * 4) =
            make_float4(acc[i][0] - bA[i], acc[i][1] - bA[i],
                        acc[i][2] - bA[i], acc[i][3] - bA[i]);
      }
      __syncthreads();  // before ms (or next chunk's xs) is overwritten
    }
  }
}

// ---------------------------------------------------------------------------
extern "C" void kernel_launch(void* const* d_in, const int* in_sizes, int n_in,
                              void* d_out, int out_size, void* d_ws,
                              size_t ws_size, hipStream_t stream) {
  const float* x = (const float*)d_in[0];        // (64,128,56,56) fp32
  const float* rot = (const float*)d_in[1];      // (128,128) fp32
  float* out = (float*)d_out;                    // (64,128,56,56) fp32
  float* ws = (float*)d_ws;

  // ws layout (floats)
  float* G      = ws;                // 16384
  float* SigmaN = ws + 16384;        // 16384
  float* Pa     = ws + 32768;        // 16384
  float* Pb     = ws + 49152;        // 16384
  float* Mt     = ws + 65536;        // 16384
  float* Sb     = ws + 81920;        // 128   (sums, then mean)
  float* bias   = ws + 82048;        // 128
  float* scal   = ws + 82176;        // 16
  float* part2  = ws + 82192;        // 32 * 16384 = 524288
  float* part2S = ws + 82192 + 524288;             // 32 * 128 = 4096
  float* partG  = ws + 82192 + 524288 + 4096;      // slots * 16384

  const size_t wsf = ws_size / 4;
  long avail = (long)wsf - (82192 + 524288 + 4096);
  int slots = (int)(avail / (16384 + 128));
  if (slots > 512) slots = 512;
  if (slots < 1) slots = 1;
  float* partS = partG + (size_t)slots * 16384;

  gram_k<<<slots, 256, 0, stream>>>(x, partG, partS, slots);
  reduce1_k<<<512, 256, 0, stream>>>(partG, partS, part2, part2S, slots);
  reduce2_k<<<16, 256, 0, stream>>>(part2, part2S, G, Sb);
  sigma_k<<<1, 256, 0, stream>>>(G, Sb, SigmaN, Pa, scal);
  float* pin = Pa;
  float* pout = Pb;
  for (int i = 0; i < 5; ++i) {
    newton_k<<<16, 256, 0, stream>>>(pin, SigmaN, pout);
    float* tmp = pin; pin = pout; pout = tmp;
  }
  rotmt_k<<<16, 256, 0, stream>>>(rot, pin, Sb, scal, Mt, bias);
  apply_k<<<784, 256, 0, stream>>>(x, Mt, bias, out);
}

// Round 3
// 301.849 us; speedup vs baseline: 2.2110x; 1.6476x over previous
//
#include <hip/hip_runtime.h>
#include <math.h>

// Problem constants (B=64, C=128, H=W=56)
#define HW 3136
#define NCHUNK 3136          // 64 batches * 49 chunks of 64 samples
#define M_TOT 200704.0f
#define EPSV 1e-5f

typedef __attribute__((ext_vector_type(8))) short bf16x8;
typedef __attribute__((ext_vector_type(4))) short short4v;
typedef __attribute__((ext_vector_type(4))) float f32x4;

__device__ inline unsigned short f2bf(float f) {  // RNE fp32->bf16
  unsigned u = __float_as_uint(f);
  u += 0x7FFFu + ((u >> 16) & 1u);
  return (unsigned short)(u >> 16);
}

// ---------------------------------------------------------------------------
// Kernel 1: partial Gram (X @ X^T) + channel sums, bf16 MFMA 16x16x32.
// grid = slots (<=512), block = 256 (4 waves). Wave w owns G row-blocks
// {2w, 2w+1} x all 8 col-blocks. Channel sums via ones-B-frag MFMA (reuses
// A-frags). LDS x-tile stride 72 bf16: b128 frag reads 2-way (free).
// D layout (m89): col = lane&15, row = quad*4 + reg.
// ---------------------------------------------------------------------------
__global__ __launch_bounds__(256, 2) void gram_k(const float* __restrict__ x,
                                                 float* __restrict__ partG,
                                                 float* __restrict__ partS,
                                                 int slots) {
  __shared__ unsigned short xs[128 * 72];  // 18432 B
  const int t = threadIdx.x;
  const int lm = t & 15, quad = (t >> 4) & 3, w = t >> 6;

  f32x4 acc[2][8];
  f32x4 sacc[2];
  const f32x4 z = {0.f, 0.f, 0.f, 0.f};
#pragma unroll
  for (int i = 0; i < 2; ++i) {
    sacc[i] = z;
#pragma unroll
    for (int j = 0; j < 8; ++j) acc[i][j] = z;
  }
  bf16x8 ones;
#pragma unroll
  for (int j = 0; j < 8; ++j) ones[j] = (short)0x3F80;  // bf16 1.0

  for (int chunk = blockIdx.x; chunk < NCHUNK; chunk += slots) {
    const int b = chunk / 49;
    const int s0 = (chunk % 49) * 64;
    __syncthreads();  // protect xs from previous iteration's readers
#pragma unroll
    for (int i = 0; i < 8; ++i) {
      const int idx4 = i * 256 + t;
      const int c = idx4 >> 4, q = idx4 & 15;
      const float4 v =
          *(const float4*)(x + (size_t)(b * 128 + c) * HW + s0 + q * 4);
      uint2 dw;
      dw.x = (unsigned)f2bf(v.x) | ((unsigned)f2bf(v.y) << 16);
      dw.y = (unsigned)f2bf(v.z) | ((unsigned)f2bf(v.w) << 16);
      *(uint2*)&xs[c * 72 + q * 4] = dw;
    }
    __syncthreads();
#pragma unroll
    for (int ks = 0; ks < 2; ++ks) {
      const int ko = ks * 32 + quad * 8;
      const bf16x8 a0 = *(const bf16x8*)&xs[((2 * w + 0) * 16 + lm) * 72 + ko];
      const bf16x8 a1 = *(const bf16x8*)&xs[((2 * w + 1) * 16 + lm) * 72 + ko];
      sacc[0] = __builtin_amdgcn_mfma_f32_16x16x32_bf16(a0, ones, sacc[0], 0, 0, 0);
      sacc[1] = __builtin_amdgcn_mfma_f32_16x16x32_bf16(a1, ones, sacc[1], 0, 0, 0);
#pragma unroll
      for (int tj = 0; tj < 8; ++tj) {
        const bf16x8 bf = *(const bf16x8*)&xs[(tj * 16 + lm) * 72 + ko];
        acc[0][tj] = __builtin_amdgcn_mfma_f32_16x16x32_bf16(a0, bf, acc[0][tj], 0, 0, 0);
        acc[1][tj] = __builtin_amdgcn_mfma_f32_16x16x32_bf16(a1, bf, acc[1][tj], 0, 0, 0);
      }
    }
  }

  float* pg = partG + (size_t)blockIdx.x * 16384;
#pragma unroll
  for (int i = 0; i < 2; ++i) {
    const int ti = 2 * w + i;
#pragma unroll
    for (int tj = 0; tj < 8; ++tj)
#pragma unroll
      for (int r = 0; r < 4; ++r)
        pg[(ti * 16 + quad * 4 + r) * 128 + tj * 16 + lm] = acc[i][tj][r];
    if (lm == 0) {
#pragma unroll
      for (int r = 0; r < 4; ++r)
        partS[blockIdx.x * 128 + ti * 16 + quad * 4 + r] = sacc[i][r];
    }
  }
}

// ---------------------------------------------------------------------------
// Kernel 2a: stage-A reduction (32 slot-groups x 16 elem-groups = 512 blocks).
// ---------------------------------------------------------------------------
__global__ __launch_bounds__(256) void reduce1_k(const float* __restrict__ partG,
                                                 const float* __restrict__ partS,
                                                 float* __restrict__ part2,
                                                 float* __restrict__ part2S,
                                                 int slots) {
  const int t = threadIdx.x;
  const int sg = blockIdx.x & 31;
  const int eg = blockIdx.x >> 5;
  const int e4 = eg * 1024 + t * 4;
  float ax = 0.f, ay = 0.f, az = 0.f, aw = 0.f;
#pragma unroll 4
  for (int s = sg; s < slots; s += 32) {
    const float4 v = *(const float4*)(partG + (size_t)s * 16384 + e4);
    ax += v.x; ay += v.y; az += v.z; aw += v.w;
  }
  *(float4*)(part2 + (size_t)sg * 16384 + e4) = make_float4(ax, ay, az, aw);
  if (eg == 0 && t < 128) {
    float sa = 0.f;
    for (int s = sg; s < slots; s += 32) sa += partS[s * 128 + t];
    part2S[sg * 128 + t] = sa;
  }
}

// ---------------------------------------------------------------------------
// Kernel 2b: stage-B reduction (16 blocks).
// ---------------------------------------------------------------------------
__global__ __launch_bounds__(256) void reduce2_k(const float* __restrict__ part2,
                                                 const float* __restrict__ part2S,
                                                 float* __restrict__ G,
                                                 float* __restrict__ Sb) {
  const int t = threadIdx.x;
  const int e4 = blockIdx.x * 1024 + t * 4;
  float ax = 0.f, ay = 0.f, az = 0.f, aw = 0.f;
#pragma unroll
  for (int sg = 0; sg < 32; ++sg) {
    const float4 v = *(const float4*)(part2 + (size_t)sg * 16384 + e4);
    ax += v.x; ay += v.y; az += v.z; aw += v.w;
  }
  *(float4*)(G + e4) = make_float4(ax, ay, az, aw);
  if (blockIdx.x == 0 && t < 128) {
    float sa = 0.f;
#pragma unroll
    for (int sg = 0; sg < 32; ++sg) sa += part2S[sg * 128 + t];
    Sb[t] = sa;
  }
}

// ---------------------------------------------------------------------------
// Kernel 3: SigmaN = trace-normalized Sigma; Pa = P1 = 1.5I - 0.5*SigmaN
// (first Newton iteration in closed form, since P0 = I). Sb -> mean;
// scal[0] = sqrt(1/trace). 1 block x 256.
// ---------------------------------------------------------------------------
__global__ __launch_bounds__(256) void sigma_k(const float* __restrict__ G,
                                               float* __restrict__ Sb,
                                               float* __restrict__ SigmaN,
                                               float* __restrict__ Pa,
                                               float* __restrict__ scal) {
  const int t = threadIdx.x;
  const float rm = 1.0f / M_TOT;
  float trl = 0.f;
#pragma unroll 4
  for (int i = 0; i < 64; ++i) {
    const int e = i * 256 + t;
    const int r = e >> 7, c = e & 127;
    float v = (G[e] - Sb[r] * Sb[c] * rm) * rm + ((r == c) ? EPSV : 0.f);
    SigmaN[e] = v;
    if (r == c) trl += v;
  }
  __shared__ float red[256];
  red[t] = trl;
  __syncthreads();
  for (int off = 128; off > 0; off >>= 1) {
    if (t < off) red[t] += red[t + off];
    __syncthreads();
  }
  const float rTr = 1.0f / red[0];
#pragma unroll 4
  for (int i = 0; i < 64; ++i) {
    const int e = i * 256 + t;
    const int r = e >> 7, c = e & 127;
    const float sn = SigmaN[e] * rTr;
    SigmaN[e] = sn;
    Pa[e] = ((r == c) ? 1.5f : 0.f) - 0.5f * sn;
  }
  if (t < 128) Sb[t] *= rm;  // mean
  if (t == 0) scal[0] = sqrtf(rTr);
}

// ---------------------------------------------------------------------------
// Kernel 4: one fused Newton iteration: Pout = 0.5*(3P - ((P@P)@P)@SigmaN).
// grid = 16 (8-row strips), block = 256. Thread tile = 4 rows x 4 cols,
// 4-way K-split (kt = wave id), LDS combine. Phase-1 A-reads exploit P's
// symmetry (P[r][k] = P[k][r]) for float4 broadcast loads. B-reads are
// coalesced float4 from L2 (P / SigmaN are hot).
// ---------------------------------------------------------------------------
__global__ __launch_bounds__(256) void newton_k(const float* __restrict__ P,
                                                const float* __restrict__ SigmaN,
                                                float* __restrict__ Pout) {
  __shared__ float s1[8 * 132];
  __shared__ float s2[8 * 132];
  __shared__ float red[256 * 17];
  const int t = threadIdx.x;
  const int ct = t & 31;        // col tile (4 cols)
  const int rt = (t >> 5) & 1;  // row pair (4 rows)
  const int kt = t >> 6;        // k quarter
  const int rg0 = blockIdx.x * 8;
  float a[4][4];

  // ---------- phase 1: s1 = strip(P @ P) ----------
#pragma unroll
  for (int i = 0; i < 4; ++i)
#pragma unroll
    for (int j = 0; j < 4; ++j) a[i][j] = 0.f;
#pragma unroll 4
  for (int k = kt * 32; k < kt * 32 + 32; ++k) {
    const float4 av = *(const float4*)(P + k * 128 + rg0 + 4 * rt);  // symmetry
    const float4 bv = *(const float4*)(P + k * 128 + 4 * ct);
    const float aA[4] = {av.x, av.y, av.z, av.w};
    const float bA[4] = {bv.x, bv.y, bv.z, bv.w};
#pragma unroll
    for (int i = 0; i < 4; ++i)
#pragma unroll
      for (int j = 0; j < 4; ++j) a[i][j] += aA[i] * bA[j];
  }
#pragma unroll
  for (int i = 0; i < 4; ++i)
#pragma unroll
    for (int j = 0; j < 4; ++j) red[t * 17 + i * 4 + j] = a[i][j];
  __syncthreads();
  if (t < 64) {
#pragma unroll
    for (int u = 1; u < 4; ++u)
#pragma unroll
      for (int i = 0; i < 4; ++i)
#pragma unroll
        for (int j = 0; j < 4; ++j)
          a[i][j] += red[(t + 64 * u) * 17 + i * 4 + j];
#pragma unroll
    for (int i = 0; i < 4; ++i)
#pragma unroll
      for (int j = 0; j < 4; ++j)
        s1[(4 * rt + i) * 132 + 4 * ct + j] = a[i][j];
  }
  __syncthreads();

  // ---------- phase 2: s2 = s1 @ P ----------
#pragma unroll
  for (int i = 0; i < 4; ++i)
#pragma unroll
    for (int j = 0; j < 4; ++j) a[i][j] = 0.f;
#pragma unroll 4
  for (int k = kt * 32; k < kt * 32 + 32; ++k) {
    float aA[4];
#pragma unroll
    for (int i = 0; i < 4; ++i) aA[i] = s1[(4 * rt + i) * 132 + k];
    const float4 bv = *(const float4*)(P + k * 128 + 4 * ct);
    const float bA[4] = {bv.x, bv.y, bv.z, bv.w};
#pragma unroll
    for (int i = 0; i < 4; ++i)
#pragma unroll
      for (int j = 0; j < 4; ++j) a[i][j] += aA[i] * bA[j];
  }
  __syncthreads();  // red reuse
#pragma unroll
  for (int i = 0; i < 4; ++i)
#pragma unroll
    for (int j = 0; j < 4; ++j) red[t * 17 + i * 4 + j] = a[i][j];
  __syncthreads();
  if (t < 64) {
#pragma unroll
    for (int u = 1; u < 4; ++u)
#pragma unroll
      for (int i = 0; i < 4; ++i)
#pragma unroll
        for (int j = 0; j < 4; ++j)
          a[i][j] += red[(t + 64 * u) * 17 + i * 4 + j];
#pragma unroll
    for (int i = 0; i < 4; ++i)
#pragma unroll
      for (int j = 0; j < 4; ++j)
        s2[(4 * rt + i) * 132 + 4 * ct + j] = a[i][j];
  }
  __syncthreads();

  // ---------- phase 3: C = s2 @ SigmaN; Pout = 0.5*(3P - C) ----------
#pragma unroll
  for (int i = 0; i < 4; ++i)
#pragma unroll
    for (int j = 0; j < 4; ++j) a[i][j] = 0.f;
#pragma unroll 4
  for (int k = kt * 32; k < kt * 32 + 32; ++k) {
    float aA[4];
#pragma unroll
    for (int i = 0; i < 4; ++i) aA[i] = s2[(4 * rt + i) * 132 + k];
    const float4 bv = *(const float4*)(SigmaN + k * 128 + 4 * ct);
    const float bA[4] = {bv.x, bv.y, bv.z, bv.w};
#pragma unroll
    for (int i = 0; i < 4; ++i)
#pragma unroll
      for (int j = 0; j < 4; ++j) a[i][j] += aA[i] * bA[j];
  }
  __syncthreads();  // red reuse
#pragma unroll
  for (int i = 0; i < 4; ++i)
#pragma unroll
    for (int j = 0; j < 4; ++j) red[t * 17 + i * 4 + j] = a[i][j];
  __syncthreads();
  if (t < 64) {
#pragma unroll
    for (int u = 1; u < 4; ++u)
#pragma unroll
      for (int i = 0; i < 4; ++i)
#pragma unroll
        for (int j = 0; j < 4; ++j)
          a[i][j] += red[(t + 64 * u) * 17 + i * 4 + j];
#pragma unroll
    for (int i = 0; i < 4; ++i) {
      const int rg = rg0 + 4 * rt + i;
      const float4 pv = *(const float4*)(P + rg * 128 + 4 * ct);
      *(float4*)(Pout + rg * 128 + 4 * ct) =
          make_float4(0.5f * (3.f * pv.x - a[i][0]),
                      0.5f * (3.f * pv.y - a[i][1]),
                      0.5f * (3.f * pv.z - a[i][2]),
                      0.5f * (3.f * pv.w - a[i][3]));
    }
  }
}

// ---------------------------------------------------------------------------
// Kernel 5: Mbf = bf16(sqrt(rTr) * rot @ P) row-major [d][c];
// bias[d] = sum_c M[d][c]*mean[c]. grid = 16, block = 256.
// ---------------------------------------------------------------------------
__global__ __launch_bounds__(256) void rotmt_k(const float* __restrict__ rot,
                                               const float* __restrict__ P,
                                               const float* __restrict__ mean,
                                               const float* __restrict__ scal,
                                               unsigned short* __restrict__ Mbf,
                                               float* __restrict__ bias) {
  const int t = threadIdx.x;
  const int r = t >> 5;
  const int dg = blockIdx.x * 8 + r;
  const int c0 = (t & 31) * 4;
  const float* rrow = rot + dg * 128;

  float ax = 0, ay = 0, az = 0, aw = 0;
#pragma unroll 4
  for (int k = 0; k < 128; ++k) {
    const float a = rrow[k];
    const float4 bv = *(const float4*)(P + k * 128 + c0);
    ax += a * bv.x; ay += a * bv.y; az += a * bv.z; aw += a * bv.w;
  }
  const float sc = scal[0];
  ax *= sc; ay *= sc; az *= sc; aw *= sc;
  uint2 dw;
  dw.x = (unsigned)f2bf(ax) | ((unsigned)f2bf(ay) << 16);
  dw.y = (unsigned)f2bf(az) | ((unsigned)f2bf(aw) << 16);
  *(uint2*)&Mbf[dg * 128 + c0] = dw;
  const float4 mv = *(const float4*)(mean + c0);
  float p = ax * mv.x + ay * mv.y + az * mv.z + aw * mv.w;
  for (int off = 16; off > 0; off >>= 1) p += __shfl_down(p, off, 32);
  if ((t & 31) == 0) bias[dg] = p;
}

// ---------------------------------------------------------------------------
// Kernel 6: out[b,d,s] = sum_c M[d][c]*x[c,s] - bias[d], bf16 MFMA.
// grid = 784 (4 chunks each), block = 256 (4 waves). Wave w owns d-blocks
// {2w,2w+1} x 4 s-blocks; K = 128 channels = 4 ksteps. M staged once per
// block (stride 136: b128 frags 2-way-free); x chunk staged transposed
// [s][c] bf16 (stride 132: b64-aligned frag halves, ~4-way on writes).
// ---------------------------------------------------------------------------
#define MSTR 136
#define XSTR 132
__global__ __launch_bounds__(256, 2) void apply_k(const float* __restrict__ x,
                                                  const unsigned short* __restrict__ Mbf,
                                                  const float* __restrict__ bias,
                                                  float* __restrict__ out) {
  __shared__ unsigned short Ms[128 * MSTR];   // 34816 B
  __shared__ unsigned short xsB[64 * XSTR];   // 16896 B
  const int t = threadIdx.x;
  const int lm = t & 15, quad = (t >> 4) & 3, w = t >> 6;

  // stage M once
#pragma unroll
  for (int i = 0; i < 8; ++i) {
    const int e = i * 256 + t;
    const int row = e >> 4, oct = e & 15;
    *(uint4*)&Ms[row * MSTR + oct * 8] =
        *(const uint4*)(Mbf + row * 128 + oct * 8);
  }
  // preload bias for this wave's d rows
  float biasr[2][4];
#pragma unroll
  for (int i = 0; i < 2; ++i)
#pragma unroll
    for (int r = 0; r < 4; ++r)
      biasr[i][r] = bias[(2 * w + i) * 16 + quad * 4 + r];

  const f32x4 z = {0.f, 0.f, 0.f, 0.f};
  for (int chunk = blockIdx.x; chunk < NCHUNK; chunk += 784) {
    const int b = chunk / 49;
    const int s0 = (chunk % 49) * 64;
    __syncthreads();  // xsB readers done (also covers Ms staging on iter 0)
    // stage x chunk transposed: pair p -> channels {2p, 2p+1}
#pragma unroll
    for (int i = 0; i < 4; ++i) {
      const int p = 16 * i + (t >> 4);
      const int q = t & 15;
      const float* px = x + (size_t)(b * 128 + 2 * p) * HW + s0 + 4 * q;
      const float4 fa = *(const float4*)px;
      const float4 fb = *(const float4*)(px + HW);
      const float faA[4] = {fa.x, fa.y, fa.z, fa.w};
      const float fbA[4] = {fb.x, fb.y, fb.z, fb.w};
#pragma unroll
      for (int r = 0; r < 4; ++r) {
        const unsigned dw =
            (unsigned)f2bf(faA[r]) | ((unsigned)f2bf(fbA[r]) << 16);
        *(unsigned*)&xsB[(4 * q + r) * XSTR + 2 * p] = dw;
      }
    }
    __syncthreads();

    f32x4 acc[2][4];
#pragma unroll
    for (int i = 0; i < 2; ++i)
#pragma unroll
      for (int sj = 0; sj < 4; ++sj) acc[i][sj] = z;

#pragma unroll
    for (int ks = 0; ks < 4; ++ks) {
      const int ko = ks * 32 + quad * 8;
      const bf16x8 a0 = *(const bf16x8*)&Ms[((2 * w + 0) * 16 + lm) * MSTR + ko];
      const bf16x8 a1 = *(const bf16x8*)&Ms[((2 * w + 1) * 16 + lm) * MSTR + ko];
#pragma unroll
      for (int sj = 0; sj < 4; ++sj) {
        const short4v blo = *(const short4v*)&xsB[(sj * 16 + lm) * XSTR + ko];
        const short4v bhi = *(const short4v*)&xsB[(sj * 16 + lm) * XSTR + ko + 4];
        const bf16x8 bf = __builtin_shufflevector(blo, bhi, 0, 1, 2, 3, 4, 5, 6, 7);
        acc[0][sj] = __builtin_amdgcn_mfma_f32_16x16x32_bf16(a0, bf, acc[0][sj], 0, 0, 0);
        acc[1][sj] = __builtin_amdgcn_mfma_f32_16x16x32_bf16(a1, bf, acc[1][sj], 0, 0, 0);
      }
    }
    // epilogue: D col = lane&15 = s, row = quad*4+reg = d-within-tile
#pragma unroll
    for (int i = 0; i < 2; ++i)
#pragma unroll
      for (int r = 0; r < 4; ++r) {
        const int d = (2 * w + i) * 16 + quad * 4 + r;
        float* orow = out + (size_t)(b * 128 + d) * HW + s0 + lm;
#pragma unroll
        for (int sj = 0; sj < 4; ++sj)
          orow[sj * 16] = acc[i][sj][r] - biasr[i][r];
      }
  }
}

// ---------------------------------------------------------------------------
extern "C" void kernel_launch(void* const* d_in, const int* in_sizes, int n_in,
                              void* d_out, int out_size, void* d_ws,
                              size_t ws_size, hipStream_t stream) {
  const float* x = (const float*)d_in[0];        // (64,128,56,56) fp32
  const float* rot = (const float*)d_in[1];      // (128,128) fp32
  float* out = (float*)d_out;                    // (64,128,56,56) fp32
  float* ws = (float*)d_ws;

  // ws layout (floats)
  float* G      = ws;                        // 16384
  float* SigmaN = ws + 16384;                // 16384
  float* Pa     = ws + 32768;                // 16384
  float* Pb     = ws + 49152;                // 16384
  unsigned short* Mbf = (unsigned short*)(ws + 65536);  // 16384 ushort = 8192 fl
  float* Sb     = ws + 73728;                // 128
  float* bias   = ws + 73856;                // 128
  float* scal   = ws + 73984;                // 16
  float* part2  = ws + 74000;                // 32*16384
  float* part2S = ws + 74000 + 524288;       // 4096
  float* partG  = ws + 74000 + 524288 + 4096;

  const size_t wsf = ws_size / 4;
  long avail = (long)wsf - (74000 + 524288 + 4096);
  int slots = (int)(avail / (16384 + 128));
  if (slots > 512) slots = 512;
  if (slots < 1) slots = 1;
  float* partS = partG + (size_t)slots * 16384;

  gram_k<<<slots, 256, 0, stream>>>(x, partG, partS, slots);
  reduce1_k<<<512, 256, 0, stream>>>(partG, partS, part2, part2S, slots);
  reduce2_k<<<16, 256, 0, stream>>>(part2, part2S, G, Sb);
  sigma_k<<<1, 256, 0, stream>>>(G, Sb, SigmaN, Pa, scal);  // Pa = P1
  float* pin = Pa;
  float* pout = Pb;
  for (int i = 0; i < 4; ++i) {  // P1 analytic + 4 iters = T=5
    newton_k<<<16, 256, 0, stream>>>(pin, SigmaN, pout);
    float* tmp = pin; pin = pout; pout = tmp;
  }
  rotmt_k<<<16, 256, 0, stream>>>(rot, pin, Sb, scal, Mbf, bias);
  apply_k<<<784, 256, 0, stream>>>(x, Mbf, bias, out);
}

// Round 4
// 263.767 us; speedup vs baseline: 2.5302x; 1.1444x over previous
//
#include <hip/hip_runtime.h>
#include <math.h>

// Problem constants (B=64, C=128, H=W=56)
#define HW 3136
#define NCHUNK 3136          // 64 batches * 49 chunks of 64 samples
#define M_TOT 200704.0f
#define EPSV 1e-5f

typedef __attribute__((ext_vector_type(8))) short bf16x8;
typedef __attribute__((ext_vector_type(4))) short short4v;
typedef __attribute__((ext_vector_type(4))) float f32x4;

__device__ inline unsigned short f2bf(float f) {  // RNE fp32->bf16
  unsigned u = __float_as_uint(f);
  u += 0x7FFFu + ((u >> 16) & 1u);
  return (unsigned short)(u >> 16);
}

// ---------------------------------------------------------------------------
// Kernel 1: partial Gram (X @ X^T) + channel sums, bf16 MFMA 16x16x32.
// grid = slots (512), block = 512 (8 waves -> 16 waves/CU at 2 blocks/CU).
// Double-buffered LDS + VGPR prefetch: next chunk's global loads issue before
// the MFMA phase and drain during it; ONE barrier per iteration (buffer k is
// re-written only two iterations after its readers, separated by a barrier).
// Wave w owns G row-block w x all 8 col-blocks (+ row-sum via ones-B MFMA).
// D layout (m89): col = lane&15, row = quad*4 + reg.
// ---------------------------------------------------------------------------
__global__ __launch_bounds__(512, 4) void gram_k(const float* __restrict__ x,
                                                 float* __restrict__ partG,
                                                 float* __restrict__ partS,
                                                 int slots) {
  __shared__ unsigned short xs[2][128 * 72];  // 2 x 18432 B
  const int t = threadIdx.x;
  const int lm = t & 15, quad = (t >> 4) & 3, w = t >> 6;  // w = 0..7
  const int row0 = w * 16;
  const int qofs = (t & 15) * 4;   // sample-quad offset for staging
  const int chi = t >> 4;          // 0..31 channel sub-index for staging

  f32x4 acc[8];
  f32x4 sacc;
  const f32x4 z = {0.f, 0.f, 0.f, 0.f};
  sacc = z;
#pragma unroll
  for (int j = 0; j < 8; ++j) acc[j] = z;
  bf16x8 ones;
#pragma unroll
  for (int j = 0; j < 8; ++j) ones[j] = (short)0x3F80;  // bf16 1.0

  int chunk = blockIdx.x;
  float4 pre[4];
  {
    const int b = chunk / 49;
    const int s0 = (chunk % 49) * 64;
    const float* base = x + (size_t)(b * 128) * HW + s0;
#pragma unroll
    for (int i = 0; i < 4; ++i)
      pre[i] = *(const float4*)(base + (size_t)(i * 32 + chi) * HW + qofs);
  }

  int buf = 0;
  while (chunk < NCHUNK) {
    // stage prefetched chunk -> xs[buf]
#pragma unroll
    for (int i = 0; i < 4; ++i) {
      const int c = i * 32 + chi;
      uint2 dw;
      dw.x = (unsigned)f2bf(pre[i].x) | ((unsigned)f2bf(pre[i].y) << 16);
      dw.y = (unsigned)f2bf(pre[i].z) | ((unsigned)f2bf(pre[i].w) << 16);
      *(uint2*)&xs[buf][c * 72 + qofs] = dw;
    }
    __syncthreads();
    // prefetch next chunk (drains during MFMA below)
    const int nxt = chunk + slots;
    if (nxt < NCHUNK) {
      const int b = nxt / 49;
      const int s0 = (nxt % 49) * 64;
      const float* base = x + (size_t)(b * 128) * HW + s0;
#pragma unroll
      for (int i = 0; i < 4; ++i)
        pre[i] = *(const float4*)(base + (size_t)(i * 32 + chi) * HW + qofs);
    }
    // compute from xs[buf]
#pragma unroll
    for (int ks = 0; ks < 2; ++ks) {
      const int ko = ks * 32 + quad * 8;
      const bf16x8 a0 = *(const bf16x8*)&xs[buf][(row0 + lm) * 72 + ko];
      sacc = __builtin_amdgcn_mfma_f32_16x16x32_bf16(a0, ones, sacc, 0, 0, 0);
#pragma unroll
      for (int tj = 0; tj < 8; ++tj) {
        const bf16x8 bf = *(const bf16x8*)&xs[buf][(tj * 16 + lm) * 72 + ko];
        acc[tj] = __builtin_amdgcn_mfma_f32_16x16x32_bf16(a0, bf, acc[tj], 0, 0, 0);
      }
    }
    buf ^= 1;
    chunk = nxt;
  }

  float* pg = partG + (size_t)blockIdx.x * 16384;
#pragma unroll
  for (int tj = 0; tj < 8; ++tj)
#pragma unroll
    for (int r = 0; r < 4; ++r)
      pg[(row0 + quad * 4 + r) * 128 + tj * 16 + lm] = acc[tj][r];
  if (lm == 0) {
#pragma unroll
    for (int r = 0; r < 4; ++r)
      partS[blockIdx.x * 128 + row0 + quad * 4 + r] = sacc[r];
  }
}

// ---------------------------------------------------------------------------
// Kernel 2: stage-A reduction (32 slot-groups x 16 elem-groups = 512 blocks).
// ---------------------------------------------------------------------------
__global__ __launch_bounds__(256) void reduce1_k(const float* __restrict__ partG,
                                                 const float* __restrict__ partS,
                                                 float* __restrict__ part2,
                                                 float* __restrict__ part2S,
                                                 int slots) {
  const int t = threadIdx.x;
  const int sg = blockIdx.x & 31;
  const int eg = blockIdx.x >> 5;
  const int e4 = eg * 1024 + t * 4;
  float ax = 0.f, ay = 0.f, az = 0.f, aw = 0.f;
#pragma unroll 4
  for (int s = sg; s < slots; s += 32) {
    const float4 v = *(const float4*)(partG + (size_t)s * 16384 + e4);
    ax += v.x; ay += v.y; az += v.z; aw += v.w;
  }
  *(float4*)(part2 + (size_t)sg * 16384 + e4) = make_float4(ax, ay, az, aw);
  if (eg == 0 && t < 128) {
    float sa = 0.f;
    for (int s = sg; s < slots; s += 32) sa += partS[s * 128 + t];
    part2S[sg * 128 + t] = sa;
  }
}

// ---------------------------------------------------------------------------
// Kernel 3: merged stage-B reduce + Sigma build. grid = 16, block = 256.
// Each block: redundantly reduce part2S -> channel sums (block 0 also writes
// mean), reduce its 1/16 of G, form RAW Sigma = (G - S S^T/m)/m + eps*I
// (NO trace normalization -- rTr is deferred: consumers read traceP[0..15]
// and fold 1/trace themselves), write per-block trace partial.
// ---------------------------------------------------------------------------
__global__ __launch_bounds__(256) void sigred_k(const float* __restrict__ part2,
                                                const float* __restrict__ part2S,
                                                float* __restrict__ Sigma,
                                                float* __restrict__ traceP,
                                                float* __restrict__ meanOut) {
  __shared__ float SbL[128];
  __shared__ float red[256];
  const int t = threadIdx.x;
  if (t < 128) {
    float sa = 0.f;
#pragma unroll
    for (int sg = 0; sg < 32; ++sg) sa += part2S[sg * 128 + t];
    SbL[t] = sa;
    if (blockIdx.x == 0) meanOut[t] = sa * (1.0f / M_TOT);
  }
  __syncthreads();
  const int e4 = blockIdx.x * 1024 + t * 4;
  float ax = 0.f, ay = 0.f, az = 0.f, aw = 0.f;
#pragma unroll
  for (int sg = 0; sg < 32; ++sg) {
    const float4 v = *(const float4*)(part2 + (size_t)sg * 16384 + e4);
    ax += v.x; ay += v.y; az += v.z; aw += v.w;
  }
  const int r = e4 >> 7, c0 = e4 & 127;
  const float rm = 1.0f / M_TOT;
  const float sr = SbL[r] * rm;
  float s4[4];
  s4[0] = (ax - sr * SbL[c0 + 0]) * rm;
  s4[1] = (ay - sr * SbL[c0 + 1]) * rm;
  s4[2] = (az - sr * SbL[c0 + 2]) * rm;
  s4[3] = (aw - sr * SbL[c0 + 3]) * rm;
  float trl = 0.f;
#pragma unroll
  for (int j = 0; j < 4; ++j) {
    if (c0 + j == r) { s4[j] += EPSV; trl = s4[j]; }
  }
  *(float4*)(Sigma + e4) = make_float4(s4[0], s4[1], s4[2], s4[3]);
  red[t] = trl;
  __syncthreads();
  for (int off = 128; off > 0; off >>= 1) {
    if (t < off) red[t] += red[t + off];
    __syncthreads();
  }
  if (t == 0) traceP[blockIdx.x] = red[0];
}

// ---------------------------------------------------------------------------
// Kernel 4a: FIRST+SECOND Newton step fused: takes raw Sigma, synthesizes
// P1 = 1.5I - 0.5*rTr*Sigma on the fly (P0=I step is analytic), computes
// P2 = 0.5*(3 P1 - P1^3 * (rTr*Sigma)). grid = 16, block = 256.
// Thread tile 4x4, 4-way K-split (kt = wave), LDS combine. A-loads use
// symmetry (P1, Sigma symmetric).
// ---------------------------------------------------------------------------
__global__ __launch_bounds__(256) void newton1_k(const float* __restrict__ Sig,
                                                 const float* __restrict__ traceP,
                                                 float* __restrict__ Pout) {
  __shared__ float s1[8 * 132];
  __shared__ float s2[8 * 132];
  __shared__ float red[256 * 17];
  const int t = threadIdx.x;
  const int ct = t & 31;        // col tile (4 cols)
  const int rt = (t >> 5) & 1;  // row pair (4 rows)
  const int kt = t >> 6;        // k quarter
  const int rg0 = blockIdx.x * 8;
  const int ra = rg0 + 4 * rt;
  float tr = 0.f;
#pragma unroll
  for (int i = 0; i < 16; ++i) tr += traceP[i];
  const float rTr = 1.0f / tr;
  const float nh = -0.5f * rTr;
  float a[4][4];

  // ---------- phase 1: s1 = strip(P1 @ P1) ----------
#pragma unroll
  for (int i = 0; i < 4; ++i)
#pragma unroll
    for (int j = 0; j < 4; ++j) a[i][j] = 0.f;
#pragma unroll 4
  for (int k = kt * 32; k < kt * 32 + 32; ++k) {
    const float4 sa4 = *(const float4*)(Sig + k * 128 + ra);   // symmetry
    const float4 sb4 = *(const float4*)(Sig + k * 128 + 4 * ct);
    float aA[4] = {nh * sa4.x, nh * sa4.y, nh * sa4.z, nh * sa4.w};
    float bA[4] = {nh * sb4.x, nh * sb4.y, nh * sb4.z, nh * sb4.w};
#pragma unroll
    for (int i = 0; i < 4; ++i) if (ra + i == k) aA[i] += 1.5f;
#pragma unroll
    for (int j = 0; j < 4; ++j) if (4 * ct + j == k) bA[j] += 1.5f;
#pragma unroll
    for (int i = 0; i < 4; ++i)
#pragma unroll
      for (int j = 0; j < 4; ++j) a[i][j] += aA[i] * bA[j];
  }
#pragma unroll
  for (int i = 0; i < 4; ++i)
#pragma unroll
    for (int j = 0; j < 4; ++j) red[t * 17 + i * 4 + j] = a[i][j];
  __syncthreads();
  if (t < 64) {
#pragma unroll
    for (int u = 1; u < 4; ++u)
#pragma unroll
      for (int i = 0; i < 4; ++i)
#pragma unroll
        for (int j = 0; j < 4; ++j)
          a[i][j] += red[(t + 64 * u) * 17 + i * 4 + j];
#pragma unroll
    for (int i = 0; i < 4; ++i)
#pragma unroll
      for (int j = 0; j < 4; ++j)
        s1[(4 * rt + i) * 132 + 4 * ct + j] = a[i][j];
  }
  __syncthreads();

  // ---------- phase 2: s2 = s1 @ P1 ----------
#pragma unroll
  for (int i = 0; i < 4; ++i)
#pragma unroll
    for (int j = 0; j < 4; ++j) a[i][j] = 0.f;
#pragma unroll 4
  for (int k = kt * 32; k < kt * 32 + 32; ++k) {
    float aA[4];
#pragma unroll
    for (int i = 0; i < 4; ++i) aA[i] = s1[(4 * rt + i) * 132 + k];
    const float4 sb4 = *(const float4*)(Sig + k * 128 + 4 * ct);
    float bA[4] = {nh * sb4.x, nh * sb4.y, nh * sb4.z, nh * sb4.w};
#pragma unroll
    for (int j = 0; j < 4; ++j) if (4 * ct + j == k) bA[j] += 1.5f;
#pragma unroll
    for (int i = 0; i < 4; ++i)
#pragma unroll
      for (int j = 0; j < 4; ++j) a[i][j] += aA[i] * bA[j];
  }
  __syncthreads();
#pragma unroll
  for (int i = 0; i < 4; ++i)
#pragma unroll
    for (int j = 0; j < 4; ++j) red[t * 17 + i * 4 + j] = a[i][j];
  __syncthreads();
  if (t < 64) {
#pragma unroll
    for (int u = 1; u < 4; ++u)
#pragma unroll
      for (int i = 0; i < 4; ++i)
#pragma unroll
        for (int j = 0; j < 4; ++j)
          a[i][j] += red[(t + 64 * u) * 17 + i * 4 + j];
#pragma unroll
    for (int i = 0; i < 4; ++i)
#pragma unroll
      for (int j = 0; j < 4; ++j)
        s2[(4 * rt + i) * 132 + 4 * ct + j] = a[i][j];
  }
  __syncthreads();

  // ---------- phase 3: a = s2 @ Sigma_raw; Pout = 0.5*(3 P1 - rTr*a) ----------
#pragma unroll
  for (int i = 0; i < 4; ++i)
#pragma unroll
    for (int j = 0; j < 4; ++j) a[i][j] = 0.f;
#pragma unroll 4
  for (int k = kt * 32; k < kt * 32 + 32; ++k) {
    float aA[4];
#pragma unroll
    for (int i = 0; i < 4; ++i) aA[i] = s2[(4 * rt + i) * 132 + k];
    const float4 bv = *(const float4*)(Sig + k * 128 + 4 * ct);
    const float bA[4] = {bv.x, bv.y, bv.z, bv.w};
#pragma unroll
    for (int i = 0; i < 4; ++i)
#pragma unroll
      for (int j = 0; j < 4; ++j) a[i][j] += aA[i] * bA[j];
  }
  __syncthreads();
#pragma unroll
  for (int i = 0; i < 4; ++i)
#pragma unroll
    for (int j = 0; j < 4; ++j) red[t * 17 + i * 4 + j] = a[i][j];
  __syncthreads();
  if (t < 64) {
#pragma unroll
    for (int u = 1; u < 4; ++u)
#pragma unroll
      for (int i = 0; i < 4; ++i)
#pragma unroll
        for (int j = 0; j < 4; ++j)
          a[i][j] += red[(t + 64 * u) * 17 + i * 4 + j];
#pragma unroll
    for (int i = 0; i < 4; ++i) {
      const int rg = rg0 + 4 * rt + i;
      const float4 sv = *(const float4*)(Sig + rg * 128 + 4 * ct);
      float p1v[4] = {nh * sv.x, nh * sv.y, nh * sv.z, nh * sv.w};
#pragma unroll
      for (int j = 0; j < 4; ++j) if (4 * ct + j == rg) p1v[j] += 1.5f;
      *(float4*)(Pout + rg * 128 + 4 * ct) =
          make_float4(0.5f * (3.f * p1v[0] - rTr * a[i][0]),
                      0.5f * (3.f * p1v[1] - rTr * a[i][1]),
                      0.5f * (3.f * p1v[2] - rTr * a[i][2]),
                      0.5f * (3.f * p1v[3] - rTr * a[i][3]));
    }
  }
}

// ---------------------------------------------------------------------------
// Kernel 4b: one Newton iteration: Pout = 0.5*(3P - ((P@P)@P)@(rTr*Sigma)).
// Same structure; P from global (symmetric), rTr folded at the end.
// ---------------------------------------------------------------------------
__global__ __launch_bounds__(256) void newton_k(const float* __restrict__ P,
                                                const float* __restrict__ Sig,
                                                const float* __restrict__ traceP,
                                                float* __restrict__ Pout) {
  __shared__ float s1[8 * 132];
  __shared__ float s2[8 * 132];
  __shared__ float red[256 * 17];
  const int t = threadIdx.x;
  const int ct = t & 31;
  const int rt = (t >> 5) & 1;
  const int kt = t >> 6;
  const int rg0 = blockIdx.x * 8;
  float tr = 0.f;
#pragma unroll
  for (int i = 0; i < 16; ++i) tr += traceP[i];
  const float rTr = 1.0f / tr;
  float a[4][4];

  // ---------- phase 1: s1 = strip(P @ P) ----------
#pragma unroll
  for (int i = 0; i < 4; ++i)
#pragma unroll
    for (int j = 0; j < 4; ++j) a[i][j] = 0.f;
#pragma unroll 4
  for (int k = kt * 32; k < kt * 32 + 32; ++k) {
    const float4 av = *(const float4*)(P + k * 128 + rg0 + 4 * rt);  // symmetry
    const float4 bv = *(const float4*)(P + k * 128 + 4 * ct);
    const float aA[4] = {av.x, av.y, av.z, av.w};
    const float bA[4] = {bv.x, bv.y, bv.z, bv.w};
#pragma unroll
    for (int i = 0; i < 4; ++i)
#pragma unroll
      for (int j = 0; j < 4; ++j) a[i][j] += aA[i] * bA[j];
  }
#pragma unroll
  for (int i = 0; i < 4; ++i)
#pragma unroll
    for (int j = 0; j < 4; ++j) red[t * 17 + i * 4 + j] = a[i][j];
  __syncthreads();
  if (t < 64) {
#pragma unroll
    for (int u = 1; u < 4; ++u)
#pragma unroll
      for (int i = 0; i < 4; ++i)
#pragma unroll
        for (int j = 0; j < 4; ++j)
          a[i][j] += red[(t + 64 * u) * 17 + i * 4 + j];
#pragma unroll
    for (int i = 0; i < 4; ++i)
#pragma unroll
      for (int j = 0; j < 4; ++j)
        s1[(4 * rt + i) * 132 + 4 * ct + j] = a[i][j];
  }
  __syncthreads();

  // ---------- phase 2: s2 = s1 @ P ----------
#pragma unroll
  for (int i = 0; i < 4; ++i)
#pragma unroll
    for (int j = 0; j < 4; ++j) a[i][j] = 0.f;
#pragma unroll 4
  for (int k = kt * 32; k < kt * 32 + 32; ++k) {
    float aA[4];
#pragma unroll
    for (int i = 0; i < 4; ++i) aA[i] = s1[(4 * rt + i) * 132 + k];
    const float4 bv = *(const float4*)(P + k * 128 + 4 * ct);
    const float bA[4] = {bv.x, bv.y, bv.z, bv.w};
#pragma unroll
    for (int i = 0; i < 4; ++i)
#pragma unroll
      for (int j = 0; j < 4; ++j) a[i][j] += aA[i] * bA[j];
  }
  __syncthreads();
#pragma unroll
  for (int i = 0; i < 4; ++i)
#pragma unroll
    for (int j = 0; j < 4; ++j) red[t * 17 + i * 4 + j] = a[i][j];
  __syncthreads();
  if (t < 64) {
#pragma unroll
    for (int u = 1; u < 4; ++u)
#pragma unroll
      for (int i = 0; i < 4; ++i)
#pragma unroll
        for (int j = 0; j < 4; ++j)
          a[i][j] += red[(t + 64 * u) * 17 + i * 4 + j];
#pragma unroll
    for (int i = 0; i < 4; ++i)
#pragma unroll
      for (int j = 0; j < 4; ++j)
        s2[(4 * rt + i) * 132 + 4 * ct + j] = a[i][j];
  }
  __syncthreads();

  // ---------- phase 3: a = s2 @ Sigma_raw; Pout = 0.5*(3P - rTr*a) ----------
#pragma unroll
  for (int i = 0; i < 4; ++i)
#pragma unroll
    for (int j = 0; j < 4; ++j) a[i][j] = 0.f;
#pragma unroll 4
  for (int k = kt * 32; k < kt * 32 + 32; ++k) {
    float aA[4];
#pragma unroll
    for (int i = 0; i < 4; ++i) aA[i] = s2[(4 * rt + i) * 132 + k];
    const float4 bv = *(const float4*)(Sig + k * 128 + 4 * ct);
    const float bA[4] = {bv.x, bv.y, bv.z, bv.w};
#pragma unroll
    for (int i = 0; i < 4; ++i)
#pragma unroll
      for (int j = 0; j < 4; ++j) a[i][j] += aA[i] * bA[j];
  }
  __syncthreads();
#pragma unroll
  for (int i = 0; i < 4; ++i)
#pragma unroll
    for (int j = 0; j < 4; ++j) red[t * 17 + i * 4 + j] = a[i][j];
  __syncthreads();
  if (t < 64) {
#pragma unroll
    for (int u = 1; u < 4; ++u)
#pragma unroll
      for (int i = 0; i < 4; ++i)
#pragma unroll
        for (int j = 0; j < 4; ++j)
          a[i][j] += red[(t + 64 * u) * 17 + i * 4 + j];
#pragma unroll
    for (int i = 0; i < 4; ++i) {
      const int rg = rg0 + 4 * rt + i;
      const float4 pv = *(const float4*)(P + rg * 128 + 4 * ct);
      *(float4*)(Pout + rg * 128 + 4 * ct) =
          make_float4(0.5f * (3.f * pv.x - rTr * a[i][0]),
                      0.5f * (3.f * pv.y - rTr * a[i][1]),
                      0.5f * (3.f * pv.z - rTr * a[i][2]),
                      0.5f * (3.f * pv.w - rTr * a[i][3]));
    }
  }
}

// ---------------------------------------------------------------------------
// Kernel 5: Mbf = bf16(sqrt(rTr) * rot @ P) row-major [d][c];
// bias[d] = sum_c M[d][c]*mean[c]. grid = 16, block = 256.
// ---------------------------------------------------------------------------
__global__ __launch_bounds__(256) void rotmt_k(const float* __restrict__ rot,
                                               const float* __restrict__ P,
                                               const float* __restrict__ mean,
                                               const float* __restrict__ traceP,
                                               unsigned short* __restrict__ Mbf,
                                               float* __restrict__ bias) {
  const int t = threadIdx.x;
  const int r = t >> 5;
  const int dg = blockIdx.x * 8 + r;
  const int c0 = (t & 31) * 4;
  const float* rrow = rot + dg * 128;
  float tr = 0.f;
#pragma unroll
  for (int i = 0; i < 16; ++i) tr += traceP[i];
  const float sc = sqrtf(1.0f / tr);

  float ax = 0, ay = 0, az = 0, aw = 0;
#pragma unroll 4
  for (int k = 0; k < 128; ++k) {
    const float a = rrow[k];
    const float4 bv = *(const float4*)(P + k * 128 + c0);
    ax += a * bv.x; ay += a * bv.y; az += a * bv.z; aw += a * bv.w;
  }
  ax *= sc; ay *= sc; az *= sc; aw *= sc;
  uint2 dw;
  dw.x = (unsigned)f2bf(ax) | ((unsigned)f2bf(ay) << 16);
  dw.y = (unsigned)f2bf(az) | ((unsigned)f2bf(aw) << 16);
  *(uint2*)&Mbf[dg * 128 + c0] = dw;
  const float4 mv = *(const float4*)(mean + c0);
  float p = ax * mv.x + ay * mv.y + az * mv.z + aw * mv.w;
  for (int off = 16; off > 0; off >>= 1) p += __shfl_down(p, off, 32);
  if ((t & 31) == 0) bias[dg] = p;
}

// ---------------------------------------------------------------------------
// Kernel 6: out[b,d,s] = sum_c M[d][c]*x[c,s] - bias[d], bf16 MFMA.
// grid = 3136 (ONE chunk per block -> 3 blocks/CU inter-block overlap, no
// intra-block serialization), block = 256 (4 waves). Wave w owns d-blocks
// {2w,2w+1} x 4 s-blocks; K = 128 channels = 4 ksteps.
// ---------------------------------------------------------------------------
#define MSTR 136
#define XSTR 132
__global__ __launch_bounds__(256, 2) void apply_k(const float* __restrict__ x,
                                                  const unsigned short* __restrict__ Mbf,
                                                  const float* __restrict__ bias,
                                                  float* __restrict__ out) {
  __shared__ unsigned short Ms[128 * MSTR];   // 34816 B
  __shared__ unsigned short xsB[64 * XSTR];   // 16896 B
  const int t = threadIdx.x;
  const int lm = t & 15, quad = (t >> 4) & 3, w = t >> 6;
  const int b = blockIdx.x / 49;
  const int s0 = (blockIdx.x % 49) * 64;

  // stage M (L2-hot) -- independent of x loads, overlaps them
#pragma unroll
  for (int i = 0; i < 8; ++i) {
    const int e = i * 256 + t;
    const int row = e >> 4, oct = e & 15;
    *(uint4*)&Ms[row * MSTR + oct * 8] =
        *(const uint4*)(Mbf + row * 128 + oct * 8);
  }
  // stage x chunk transposed: pair p -> channels {2p, 2p+1}
#pragma unroll
  for (int i = 0; i < 4; ++i) {
    const int p = 16 * i + (t >> 4);
    const int q = t & 15;
    const float* px = x + (size_t)(b * 128 + 2 * p) * HW + s0 + 4 * q;
    const float4 fa = *(const float4*)px;
    const float4 fb = *(const float4*)(px + HW);
    const float faA[4] = {fa.x, fa.y, fa.z, fa.w};
    const float fbA[4] = {fb.x, fb.y, fb.z, fb.w};
#pragma unroll
    for (int r = 0; r < 4; ++r) {
      const unsigned dw =
          (unsigned)f2bf(faA[r]) | ((unsigned)f2bf(fbA[r]) << 16);
      *(unsigned*)&xsB[(4 * q + r) * XSTR + 2 * p] = dw;
    }
  }
  float biasr[2][4];
#pragma unroll
  for (int i = 0; i < 2; ++i)
#pragma unroll
    for (int r = 0; r < 4; ++r)
      biasr[i][r] = bias[(2 * w + i) * 16 + quad * 4 + r];
  __syncthreads();

  const f32x4 z = {0.f, 0.f, 0.f, 0.f};
  f32x4 acc[2][4];
#pragma unroll
  for (int i = 0; i < 2; ++i)
#pragma unroll
    for (int sj = 0; sj < 4; ++sj) acc[i][sj] = z;

#pragma unroll
  for (int ks = 0; ks < 4; ++ks) {
    const int ko = ks * 32 + quad * 8;
    const bf16x8 a0 = *(const bf16x8*)&Ms[((2 * w + 0) * 16 + lm) * MSTR + ko];
    const bf16x8 a1 = *(const bf16x8*)&Ms[((2 * w + 1) * 16 + lm) * MSTR + ko];
#pragma unroll
    for (int sj = 0; sj < 4; ++sj) {
      const short4v blo = *(const short4v*)&xsB[(sj * 16 + lm) * XSTR + ko];
      const short4v bhi = *(const short4v*)&xsB[(sj * 16 + lm) * XSTR + ko + 4];
      const bf16x8 bf = __builtin_shufflevector(blo, bhi, 0, 1, 2, 3, 4, 5, 6, 7);
      acc[0][sj] = __builtin_amdgcn_mfma_f32_16x16x32_bf16(a0, bf, acc[0][sj], 0, 0, 0);
      acc[1][sj] = __builtin_amdgcn_mfma_f32_16x16x32_bf16(a1, bf, acc[1][sj], 0, 0, 0);
    }
  }
  // epilogue: D col = lane&15 = s, row = quad*4+reg = d-within-tile
#pragma unroll
  for (int i = 0; i < 2; ++i)
#pragma unroll
    for (int r = 0; r < 4; ++r) {
      const int d = (2 * w + i) * 16 + quad * 4 + r;
      float* orow = out + (size_t)(b * 128 + d) * HW + s0 + lm;
#pragma unroll
      for (int sj = 0; sj < 4; ++sj)
        orow[sj * 16] = acc[i][sj][r] - biasr[i][r];
    }
}

// ---------------------------------------------------------------------------
extern "C" void kernel_launch(void* const* d_in, const int* in_sizes, int n_in,
                              void* d_out, int out_size, void* d_ws,
                              size_t ws_size, hipStream_t stream) {
  const float* x = (const float*)d_in[0];        // (64,128,56,56) fp32
  const float* rot = (const float*)d_in[1];      // (128,128) fp32
  float* out = (float*)d_out;                    // (64,128,56,56) fp32
  float* ws = (float*)d_ws;

  // ws layout (floats)
  float* Sigma  = ws;                        // 16384 (raw, eps included)
  float* Pa     = ws + 16384;                // 16384
  float* Pb     = ws + 32768;                // 16384
  unsigned short* Mbf = (unsigned short*)(ws + 49152);  // 16384 ushort
  float* Sb     = ws + 57344;                // 128 (mean)
  float* bias   = ws + 57472;                // 128
  float* traceP = ws + 57600;                // 16
  float* part2  = ws + 57616;                // 32*16384 = 524288
  float* part2S = ws + 57616 + 524288;       // 4096
  float* partG  = ws + 57616 + 524288 + 4096;

  const size_t wsf = ws_size / 4;
  long avail = (long)wsf - (57616 + 524288 + 4096);
  int slots = (int)(avail / (16384 + 128));
  if (slots > 512) slots = 512;
  if (slots < 1) slots = 1;
  float* partS = partG + (size_t)slots * 16384;

  gram_k<<<slots, 512, 0, stream>>>(x, partG, partS, slots);
  reduce1_k<<<512, 256, 0, stream>>>(partG, partS, part2, part2S, slots);
  sigred_k<<<16, 256, 0, stream>>>(part2, part2S, Sigma, traceP, Sb);
  newton1_k<<<16, 256, 0, stream>>>(Sigma, traceP, Pb);         // -> P2
  newton_k<<<16, 256, 0, stream>>>(Pb, Sigma, traceP, Pa);      // -> P3
  newton_k<<<16, 256, 0, stream>>>(Pa, Sigma, traceP, Pb);      // -> P4
  newton_k<<<16, 256, 0, stream>>>(Pb, Sigma, traceP, Pa);      // -> P5
  rotmt_k<<<16, 256, 0, stream>>>(rot, Pa, Sb, traceP, Mbf, bias);
  apply_k<<<3136, 256, 0, stream>>>(x, Mbf, bias, out);
}